// Round 1
// baseline (236.218 us; speedup 1.0000x reference)
//
#include <hip/hip_runtime.h>
#include <hip/hip_bf16.h>

// Problem constants (from reference)
#define E_TOTAL 300000
#define NDIM    128      // node feature dim
#define KDIM    256      // 2*NDIM = GEMM K
#define HDIM    512      // 2*HIDDEN = GEMM N (both MLP branches fused)
#define BN_EPS  1e-5f

// LDS padding (bf16 units). Row strides stay 16B-multiples for ds_read_b128.
#define APAD 264         // 256 + 8
#define BPAD 40          // 32 + 8

typedef __attribute__((ext_vector_type(8))) short bf16x8;
typedef __attribute__((ext_vector_type(4))) float f32x4;

__device__ __forceinline__ unsigned short f2bf(float f) {
  unsigned u = __float_as_uint(f);
  u += 0x7fffu + ((u >> 16) & 1u);   // round-to-nearest-even
  return (unsigned short)(u >> 16);
}

// Build B^T (col-major-by-hidden, bf16, BN scale folded) + folded bias + w2.
// Wcr layout: [HDIM][KDIM] bf16 (row = hidden col j, contiguous in k).
// Col j<256: branch 1 (identity). Col j>=256: branch 2 (roll): uses W1[(k+16)%256].
__global__ void prep_kernel(const float* __restrict__ W1, const float* __restrict__ b1,
                            const float* __restrict__ gamma, const float* __restrict__ beta,
                            const float* __restrict__ mean, const float* __restrict__ var,
                            const float* __restrict__ W2,
                            unsigned short* __restrict__ Wcr,
                            float* __restrict__ cbias, float* __restrict__ w2c) {
  int j = blockIdx.x;            // 0..511
  int jj = j & 255;
  float s = gamma[jj] * rsqrtf(var[jj] + BN_EPS);
  float t = beta[jj] - mean[jj] * s;
  int shift = (j >= 256) ? 16 : 0;
  for (int k = threadIdx.x; k < KDIM; k += blockDim.x) {
    int ks = (k + shift) & 255;
    Wcr[j * KDIM + k] = f2bf(W1[ks * 256 + jj] * s);
  }
  if (threadIdx.x == 0) {
    cbias[j] = b1[jj] * s + t;
    w2c[j]  = W2[jj];
  }
}

// Main fused kernel: 64 edges per block, 256 threads = 4 waves.
// Wave w owns hidden cols [w*128, w*128+128).
__global__ __launch_bounds__(256, 2) void edge_mlp_kernel(
    const float* __restrict__ node_feat, const int* __restrict__ eidx,
    const unsigned short* __restrict__ Wcr, const float* __restrict__ cbias,
    const float* __restrict__ w2c, const float* __restrict__ b2,
    float* __restrict__ out) {
  __shared__ unsigned short Al[64 * APAD];    // A tile: 64 edges x 256 k (bf16)
  __shared__ unsigned short Bl[HDIM * BPAD];  // B^T tile: 512 cols x 32 k (bf16)
  __shared__ float partial[4][64];

  const int tid  = threadIdx.x;
  const int wave = tid >> 6;
  const int lane = tid & 63;
  const int l16  = lane & 15;
  const int quad = lane >> 4;
  const int e0   = blockIdx.x * 64;

  // ---- Stage A: gather endpoint features, convert fp32->bf16, write LDS ----
  {
    int el   = tid >> 2;               // local edge 0..63
    int part = tid & 3;                // 4 x 64-float chunks per edge
    int e = e0 + el; if (e >= E_TOTAL) e = E_TOTAL - 1;   // clamp (stores guarded later)
    int node = (part < 2) ? eidx[e] : eidx[E_TOTAL + e];
    const float4* src = (const float4*)(node_feat + (long)node * NDIM + (part & 1) * 64);
    unsigned short* dst = Al + el * APAD + part * 64;
    #pragma unroll
    for (int i = 0; i < 16; i++) {
      float4 v = src[i];
      ushort4 o;
      o.x = f2bf(v.x); o.y = f2bf(v.y); o.z = f2bf(v.z); o.w = f2bf(v.w);
      ((ushort4*)dst)[i] = o;
    }
  }

  // Per-lane epilogue constants: bias & w2 for my 8 columns
  float cj[8], w2j[8];
  #pragma unroll
  for (int nt = 0; nt < 8; nt++) {
    int j = wave * 128 + nt * 16 + l16;
    cj[nt]  = cbias[j];
    w2j[nt] = w2c[j];
  }

  f32x4 acc[4][8];
  #pragma unroll
  for (int mt = 0; mt < 4; mt++)
    #pragma unroll
    for (int nt = 0; nt < 8; nt++)
      acc[mt][nt] = (f32x4){0.f, 0.f, 0.f, 0.f};

  // ---- K loop: 8 steps of 32 ----
  for (int kt = 0; kt < 8; kt++) {
    __syncthreads();   // previous Bl consumers done (also covers A staging at kt=0)
    // Stage B^T k-slice: 512 cols x 32 k. 2048 16B chunks, 8 per thread.
    #pragma unroll
    for (int i = 0; i < 8; i++) {
      int cid = tid + (i << 8);
      int col = cid >> 2, kc = cid & 3;
      const uint4* src = (const uint4*)(Wcr + col * KDIM + kt * 32 + kc * 8);
      *(uint4*)(Bl + col * BPAD + kc * 8) = *src;
    }
    __syncthreads();

    // A fragments for this k-step (4 M-tiles)
    bf16x8 af[4];
    #pragma unroll
    for (int mt = 0; mt < 4; mt++)
      af[mt] = *(const bf16x8*)(Al + (mt * 16 + l16) * APAD + kt * 32 + quad * 8);

    #pragma unroll
    for (int nt = 0; nt < 8; nt++) {
      bf16x8 bfr = *(const bf16x8*)(Bl + (wave * 128 + nt * 16 + l16) * BPAD + quad * 8);
      #pragma unroll
      for (int mt = 0; mt < 4; mt++)
        acc[mt][nt] = __builtin_amdgcn_mfma_f32_16x16x32_bf16(af[mt], bfr, acc[mt][nt], 0, 0, 0);
    }
  }

  // ---- Epilogue: relu(h+c)*w2, reduce over cols ----
  // C/D layout: col = lane&15, row = quad*4 + r (within 16x16 tile)
  #pragma unroll
  for (int mt = 0; mt < 4; mt++) {
    #pragma unroll
    for (int r = 0; r < 4; r++) {
      float v = 0.f;
      #pragma unroll
      for (int nt = 0; nt < 8; nt++) {
        float h = acc[mt][nt][r] + cj[nt];
        v += fmaxf(h, 0.f) * w2j[nt];
      }
      // sum over the 16 columns held by my 16-lane group
      v += __shfl_xor(v, 1);
      v += __shfl_xor(v, 2);
      v += __shfl_xor(v, 4);
      v += __shfl_xor(v, 8);
      if (l16 == 0) partial[wave][mt * 16 + quad * 4 + r] = v;
    }
  }
  __syncthreads();

  if (tid < 64) {
    int e = e0 + tid;
    if (e < E_TOTAL) {
      float s = partial[0][tid] + partial[1][tid] + partial[2][tid] + partial[3][tid];
      float logit = 0.5f * s + b2[0];
      out[e] = 1.0f / (1.0f + __expf(-logit));
    }
  }
}

extern "C" void kernel_launch(void* const* d_in, const int* in_sizes, int n_in,
                              void* d_out, int out_size, void* d_ws, size_t ws_size,
                              hipStream_t stream) {
  const float* node_feat = (const float*)d_in[0];
  const int*   eidx      = (const int*)d_in[1];
  const float* W1        = (const float*)d_in[2];
  const float* b1        = (const float*)d_in[3];
  const float* gamma     = (const float*)d_in[4];
  const float* beta      = (const float*)d_in[5];
  const float* mean      = (const float*)d_in[6];
  const float* var       = (const float*)d_in[7];
  const float* W2        = (const float*)d_in[8];
  const float* b2        = (const float*)d_in[9];
  float* out = (float*)d_out;

  // Workspace layout: Wcr bf16 [512][256] (256 KB) | cbias f32[512] | w2c f32[512]
  unsigned short* Wcr = (unsigned short*)d_ws;
  float* cbias = (float*)((char*)d_ws + (size_t)HDIM * KDIM * 2);
  float* w2c   = cbias + HDIM;

  prep_kernel<<<HDIM, 64, 0, stream>>>(W1, b1, gamma, beta, mean, var, W2, Wcr, cbias, w2c);

  int nblocks = (E_TOTAL + 63) / 64;   // 4688
  edge_mlp_kernel<<<nblocks, 256, 0, stream>>>(node_feat, eidx, Wcr, cbias, w2c, b2, out);
}